// Round 1
// baseline (1079.736 us; speedup 1.0000x reference)
//
#include <hip/hip_runtime.h>

// Problem constants (from reference): bsx = bsy = 1.0, XL = YL = 0.
#define NBX 1024
#define NBY 1024
static constexpr int NUM_NODES   = 4000000;
static constexpr int NUM_PHYS    = 3000000;
static constexpr int NUM_MOVABLE = 2500000;

// ---------------------------------------------------------------------------
// Kernel 1: scatter pin density into the bin map (atomic accumulate).
// One thread per physical node. Window is 4x4 but only bins with positive
// overlap contribute (avg ~6.4 atomics/node).
// ---------------------------------------------------------------------------
__global__ void __launch_bounds__(256)
scatter_pin(const float* __restrict__ pos,
            const float* __restrict__ nsx,
            const float* __restrict__ nsy,
            const int*   __restrict__ pw,
            float*       __restrict__ pmap) {
    int i = blockIdx.x * blockDim.x + threadIdx.x;
    if (i >= NUM_PHYS) return;

    float sx = nsx[i];
    float sy = nsy[i];
    float hx = 0.5f * fmaxf(1.414f, sx);   // bsx * PIN_STRETCH_RATIO = 1.414
    float hy = 0.5f * fmaxf(1.414f, sy);
    float cx = pos[i]             + 0.5f * sx;
    float cy = pos[NUM_NODES + i] + 0.5f * sy;
    float xmin = cx - hx, xmax = cx + hx;
    float ymin = cy - hy, ymax = cy + hy;
    float dens = (float)pw[i] / (4.0f * hx * hy);

    int bxl = min(max((int)floorf(xmin), 0), NBX - 1);
    int byl = min(max((int)floorf(ymin), 0), NBY - 1);

    #pragma unroll
    for (int di = 0; di < 4; ++di) {
        int bx = bxl + di;
        if (bx >= NBX) break;
        float bl = (float)bx;
        float ox = fminf(xmax, bl + 1.0f) - fmaxf(xmin, bl);
        if (ox <= 0.0f) continue;
        float dox  = dens * ox;
        int   base = bx * NBY;
        #pragma unroll
        for (int dj = 0; dj < 4; ++dj) {
            int by = byl + dj;
            if (by >= NBY) break;
            float bly = (float)by;
            float oy  = fminf(ymax, bly + 1.0f) - fmaxf(ymin, bly);
            if (oy > 0.0f)
                atomicAdd(&pmap[base + by], dox * oy);
        }
    }
}

// ---------------------------------------------------------------------------
// Kernel 2: gather adjusted overlap area per movable node.
// adj = clip(pmap * 0.5, 0.4, 2.5) fused here (bsx*bsy == 1).
// ---------------------------------------------------------------------------
__global__ void __launch_bounds__(256)
gather_area(const float* __restrict__ pos,
            const float* __restrict__ nsx,
            const float* __restrict__ nsy,
            const float* __restrict__ pmap,
            float*       __restrict__ out) {
    int i = blockIdx.x * blockDim.x + threadIdx.x;
    if (i >= NUM_MOVABLE) return;

    float mx = pos[i];
    float my = pos[NUM_NODES + i];
    float xmax = mx + nsx[i];
    float ymax = my + nsy[i];

    int bxl = min(max((int)floorf(mx), 0), NBX - 1);
    int byl = min(max((int)floorf(my), 0), NBY - 1);

    float area = 0.0f;
    #pragma unroll
    for (int di = 0; di < 4; ++di) {
        int bx = bxl + di;
        if (bx >= NBX) break;
        float bl = (float)bx;
        float ox = fminf(xmax, bl + 1.0f) - fmaxf(mx, bl);
        if (ox <= 0.0f) continue;
        int base = bx * NBY;
        #pragma unroll
        for (int dj = 0; dj < 4; ++dj) {
            int by = byl + dj;
            if (by >= NBY) break;
            float bly = (float)by;
            float oy  = fminf(ymax, bly + 1.0f) - fmaxf(my, bly);
            if (oy > 0.0f) {
                float adj = fminf(fmaxf(pmap[base + by] * 0.5f, 0.4f), 2.5f);
                area += ox * oy * adj;
            }
        }
    }
    out[i] = area;
}

// ---------------------------------------------------------------------------
extern "C" void kernel_launch(void* const* d_in, const int* in_sizes, int n_in,
                              void* d_out, int out_size, void* d_ws, size_t ws_size,
                              hipStream_t stream) {
    const float* pos = (const float*)d_in[0];
    const float* nsx = (const float*)d_in[1];
    const float* nsy = (const float*)d_in[2];
    const int*   pw  = (const int*)d_in[3];
    float* out  = (float*)d_out;
    float* pmap = (float*)d_ws;   // 1024*1024 floats = 4 MB scratch

    // Zero the bin map every call (d_ws is poisoned to 0xAA before each launch).
    hipMemsetAsync(pmap, 0, NBX * NBY * sizeof(float), stream);

    scatter_pin<<<(NUM_PHYS + 255) / 256, 256, 0, stream>>>(pos, nsx, nsy, pw, pmap);
    gather_area<<<(NUM_MOVABLE + 255) / 256, 256, 0, stream>>>(pos, nsx, nsy, pmap, out);
}